// Round 4
// baseline (1764.338 us; speedup 1.0000x reference)
//
#include <hip/hip_runtime.h>
#include <stdint.h>
#include <stddef.h>

typedef _Float16 f16;
typedef _Float16 f16x8 __attribute__((ext_vector_type(8)));
typedef _Float16 f16x4_t __attribute__((ext_vector_type(4)));
typedef float floatx4 __attribute__((ext_vector_type(4)));

template <int N> struct F16Vec { typedef f16 type __attribute__((ext_vector_type(N))); };

#define BN_EPS 1e-5f

// ---------------------------------------------------------------------------
// batched LDS-tiled weight transpose-convert: W [K,N] fp32 -> Wt [N,K] fp16
// ---------------------------------------------------------------------------
struct WtJob { const float* W; f16* Wt; int K; int N; int tN; int tilebase; };
struct WtBatch { WtJob j[12]; int njobs; int ntiles; };

__global__ void k_wt_tiled(WtBatch b) {
  __shared__ float T[32][33];
  int bt = blockIdx.x;
  int i = 0;
  #pragma unroll 1
  while (i + 1 < b.njobs && bt >= b.j[i + 1].tilebase) ++i;
  WtJob J = b.j[i];
  int t = bt - J.tilebase;
  int tr = t / J.tN, tc = t - tr * J.tN;
  int ty = threadIdx.x >> 5, tx = threadIdx.x & 31;
  #pragma unroll
  for (int s = 0; s < 32; s += 8) {
    int k = tr * 32 + ty + s, n = tc * 32 + tx;
    if (k < J.K && n < J.N) T[ty + s][tx] = J.W[(size_t)k * J.N + n];
  }
  __syncthreads();
  #pragma unroll
  for (int s = 0; s < 32; s += 8) {
    int n = tc * 32 + ty + s, k = tr * 32 + tx;
    if (n < J.N && k < J.K) J.Wt[(size_t)n * J.K + k] = (f16)T[tx][ty + s];
  }
}

// fp32 [n,c] -> fp16 into dst[r*ldd + coff + j]  (c % 4 == 0)
__global__ void k_cvt_cols(const float* __restrict__ src, f16* __restrict__ dst,
                           int n, int c, int ldd, int coff) {
  int t = blockIdx.x * blockDim.x + threadIdx.x;
  int cq = c >> 2;
  if (t >= n * cq) return;
  int r = t / cq, j = (t - r * cq) << 2;
  float4 v = *(const float4*)(src + (size_t)r * c + j);
  f16x4_t o; o[0] = (f16)v.x; o[1] = (f16)v.y; o[2] = (f16)v.z; o[3] = (f16)v.w;
  *(f16x4_t*)(dst + (size_t)r * ldd + coff + j) = o;
}

// ---------------------------------------------------------------------------
// CSR build
// ---------------------------------------------------------------------------
__global__ void k_count2(const int* __restrict__ dL, int EL, int* __restrict__ cntL,
                         const int* __restrict__ dJ, int EJ, int* __restrict__ cntJ) {
  int t = blockIdx.x * blockDim.x + threadIdx.x;
  if (t < EL) atomicAdd(&cntL[dL[t]], 1);
  else if (t < EL + EJ) atomicAdd(&cntJ[dJ[t - EL]], 1);
}

// 2 blocks: block 0 scans L, block 1 scans J. 1024 thr, 4 elems/thread/strip.
__global__ void k_scan4_dual(const int* __restrict__ cntL, int nL, int* __restrict__ rsL,
                             float* __restrict__ disL,
                             const int* __restrict__ cntJ, int nJ, int* __restrict__ rsJ,
                             float* __restrict__ disJ) {
  const int* cnt; int n; int* rowstart; float* dis;
  if (blockIdx.x == 0) { cnt = cntL; n = nL; rowstart = rsL; dis = disL; }
  else                 { cnt = cntJ; n = nJ; rowstart = rsJ; dis = disJ; }
  __shared__ int wsum[16];
  __shared__ int carry_s;
  int tid = threadIdx.x, lane = tid & 63, wv = tid >> 6;
  if (tid == 0) { carry_s = 0; rowstart[0] = 0; }
  __syncthreads();
  for (int base = 0; base < n; base += 4096) {
    int i4 = base + tid * 4;
    int4 c = {0, 0, 0, 0};
    if (i4 < n) c = *(const int4*)(cnt + i4);
    int s0 = c.x, s1 = s0 + c.y, s2 = s1 + c.z, s3 = s2 + c.w;
    int x = s3;
    #pragma unroll
    for (int off = 1; off < 64; off <<= 1) {
      int y = __shfl_up(x, off, 64);
      if (lane >= off) x += y;
    }
    if (lane == 63) wsum[wv] = x;
    __syncthreads();
    if (wv == 0) {
      int s = (lane < 16) ? wsum[lane] : 0;
      #pragma unroll
      for (int off = 1; off < 16; off <<= 1) {
        int y = __shfl_up(s, off, 64);
        if (lane >= off) s += y;
      }
      if (lane < 16) wsum[lane] = s;
    }
    __syncthreads();
    int waveoff = (wv == 0) ? 0 : wsum[wv - 1];
    int excl = (x - s3) + waveoff + carry_s;
    if (i4 < n) {
      rowstart[i4 + 1] = excl + s0;
      rowstart[i4 + 2] = excl + s1;
      rowstart[i4 + 3] = excl + s2;
      rowstart[i4 + 4] = excl + s3;
      dis[i4 + 0] = rsqrtf(1.0f + (float)c.x);
      dis[i4 + 1] = rsqrtf(1.0f + (float)c.y);
      dis[i4 + 2] = rsqrtf(1.0f + (float)c.z);
      dis[i4 + 3] = rsqrtf(1.0f + (float)c.w);
    }
    __syncthreads();
    if (tid == 1023) carry_s = excl + s3;
    __syncthreads();
  }
}

__global__ void k_fill2(const int* __restrict__ eiL, int EL, const int* __restrict__ rsL,
                        int* __restrict__ fillL, int* __restrict__ cixL,
                        const int* __restrict__ eiJ, int EJ, const int* __restrict__ rsJ,
                        int* __restrict__ fillJ, int* __restrict__ cixJ) {
  int t = blockIdx.x * blockDim.x + threadIdx.x;
  if (t < EL) {
    int s = eiL[t], d = eiL[EL + t];
    int pos = atomicAdd(&fillL[d], 1);
    cixL[rsL[d] + pos] = s;
  } else if (t < EL + EJ) {
    int u = t - EL;
    int s = eiJ[u], d = eiJ[EJ + u];
    int pos = atomicAdd(&fillJ[d], 1);
    cixJ[rsJ[d] + pos] = s;
  }
}

// ---------------------------------------------------------------------------
// GCN aggregation: one WAVE per node, CPL channels/lane, writes f16 into the
// concat slice (bias folded). acc fp32.
// ---------------------------------------------------------------------------
template <int CPL>
__global__ void k_gather_f16(const f16* __restrict__ xw, int C,
                             const int* __restrict__ rowstart, const int* __restrict__ colidx,
                             const float* __restrict__ dis, const float* __restrict__ bias,
                             f16* __restrict__ dst, int ldd, int coff, int n) {
  typedef typename F16Vec<CPL>::type V;
  int w = threadIdx.x >> 6, l = threadIdx.x & 63;
  int j = blockIdx.x * 4 + w;
  if (j >= n) return;
  float dj = dis[j];
  int rs = rowstart[j], re = rowstart[j + 1];
  int c0 = l * CPL;
  float acc[CPL];
  {
    V p = *(const V*)(xw + (size_t)j * C + c0);
    float s = dj * dj;
    #pragma unroll
    for (int t = 0; t < CPL; ++t) acc[t] = (float)p[t] * s;
  }
  int e = rs;
  for (; e + 2 <= re; e += 2) {
    int s0 = colidx[e], s1 = colidx[e + 1];
    float f0 = dis[s0] * dj, f1 = dis[s1] * dj;
    V p0 = *(const V*)(xw + (size_t)s0 * C + c0);
    V p1 = *(const V*)(xw + (size_t)s1 * C + c0);
    #pragma unroll
    for (int t = 0; t < CPL; ++t) acc[t] += (float)p0[t] * f0 + (float)p1[t] * f1;
  }
  if (e < re) {
    int s0 = colidx[e];
    float f0 = dis[s0] * dj;
    V p0 = *(const V*)(xw + (size_t)s0 * C + c0);
    #pragma unroll
    for (int t = 0; t < CPL; ++t) acc[t] += (float)p0[t] * f0;
  }
  V o;
  #pragma unroll
  for (int t = 0; t < CPL; ++t) o[t] = (f16)(acc[t] + bias[c0 + t]);
  *(V*)(dst + (size_t)j * ldd + coff + c0) = o;
}

// ---------------------------------------------------------------------------
// BatchNorm: stats -> apply (params computed inline, +relu, in place)
// ---------------------------------------------------------------------------
__global__ void k_stats(const f16* __restrict__ v, int ldd, int coff, int n, int C,
                        float* __restrict__ sum, float* __restrict__ sumsq) {
  int c = blockIdx.x * blockDim.x + threadIdx.x;
  if (c >= C) return;
  int r0 = blockIdx.y * 128, r1 = min(r0 + 128, n);
  float s = 0.f, s2 = 0.f;
  for (int r = r0; r < r1; ++r) {
    float x = (float)v[(size_t)r * ldd + coff + c];
    s += x; s2 += x * x;
  }
  atomicAdd(&sum[c], s);
  atomicAdd(&sumsq[c], s2);
}

__global__ void k_bnapply_ip(f16* __restrict__ v, int ldd, int coff, int n, int C,
                             const float* __restrict__ sum, const float* __restrict__ sumsq,
                             const float* __restrict__ gamma, const float* __restrict__ beta,
                             float invn) {
  int t = blockIdx.x * blockDim.x + threadIdx.x;
  int cq = C >> 2;
  if (t >= n * cq) return;
  int r = t / cq, c = (t - r * cq) << 2;
  float4 s4 = *(const float4*)(sum + c);
  float4 q4 = *(const float4*)(sumsq + c);
  float4 g4 = *(const float4*)(gamma + c);
  float4 b4 = *(const float4*)(beta + c);
  float m0 = s4.x * invn, m1 = s4.y * invn, m2 = s4.z * invn, m3 = s4.w * invn;
  float sc0 = g4.x * rsqrtf(q4.x * invn - m0 * m0 + BN_EPS);
  float sc1 = g4.y * rsqrtf(q4.y * invn - m1 * m1 + BN_EPS);
  float sc2 = g4.z * rsqrtf(q4.z * invn - m2 * m2 + BN_EPS);
  float sc3 = g4.w * rsqrtf(q4.w * invn - m3 * m3 + BN_EPS);
  float sh0 = b4.x - m0 * sc0, sh1 = b4.y - m1 * sc1;
  float sh2 = b4.z - m2 * sc2, sh3 = b4.w - m3 * sc3;
  f16* p = v + (size_t)r * ldd + coff + c;
  f16x4_t x = *(f16x4_t*)p;
  f16x4_t o;
  o[0] = (f16)fmaxf((float)x[0] * sc0 + sh0, 0.f);
  o[1] = (f16)fmaxf((float)x[1] * sc1 + sh1, 0.f);
  o[2] = (f16)fmaxf((float)x[2] * sc2 + sh2, 0.f);
  o[3] = (f16)fmaxf((float)x[3] * sc3 + sh3, 0.f);
  *(f16x4_t*)p = o;
}

// ---------------------------------------------------------------------------
// BIG fp16 MFMA GEMM: 128x128 tile, BK=32, 3-slot LDS ring, prefetch dist 2,
// manual s_waitcnt(vmcnt(4),lgkm(0)) + raw s_barrier — NO __syncthreads in the
// K-loop, so no compiler vmcnt(0) drain; loads stay in flight ~2 periods.
// Slots are distinct __shared__ objects (alias disambiguation for waitcnt).
// ---------------------------------------------------------------------------
#define GLL(gp, lp) \
  __builtin_amdgcn_global_load_lds( \
      (const __attribute__((address_space(1))) void*)(gp), \
      (__attribute__((address_space(3))) void*)(lp), 16, 0, 0)

#define STAGE(AS, BS) \
  do { \
    _Pragma("unroll") \
    for (int j_ = 0; j_ < 2; ++j_) { \
      GLL(ag[j_], (char*)(AS) + lof[j_]); \
      GLL(bg[j_], (char*)(BS) + lof[j_]); \
      ag[j_] += 32; bg[j_] += 32; \
    } \
  } while (0)

#define PHASE(CA, CB, NA, NB) \
  do { \
    if (i + 1 < nk) __builtin_amdgcn_s_waitcnt(116);  /* vmcnt(4) lgkm(0) */ \
    else            __builtin_amdgcn_s_waitcnt(112);  /* vmcnt(0) lgkm(0) */ \
    __builtin_amdgcn_s_barrier(); \
    f16x8 af[4], bf[4]; \
    _Pragma("unroll") \
    for (int ii = 0; ii < 4; ++ii) { \
      af[ii] = *(const f16x8*)((const char*)(CA) + aoffb[ii]); \
      bf[ii] = *(const f16x8*)((const char*)(CB) + boffb[ii]); \
    } \
    if (i + 2 < nk) { STAGE(NA, NB); } \
    _Pragma("unroll") \
    for (int mi = 0; mi < 4; ++mi) \
      _Pragma("unroll") \
      for (int ni = 0; ni < 4; ++ni) \
        acc[mi][ni] = __builtin_amdgcn_mfma_f32_16x16x32_f16(af[mi], bf[ni], acc[mi][ni], 0, 0, 0); \
    ++i; \
  } while (0)

__global__ __launch_bounds__(256)
void k_gemm_big(const f16* __restrict__ A, int lda,
                const f16* __restrict__ Bt,
                void* __restrict__ Cv, int ldc,
                const float* __restrict__ bias, int relu, int outf,
                int M, int N, int K, int mt, int nt, int per) {
  __shared__ f16 Ash0[128 * 32]; __shared__ f16 Ash1[128 * 32]; __shared__ f16 Ash2[128 * 32];
  __shared__ f16 Bsh0[128 * 32]; __shared__ f16 Bsh1[128 * 32]; __shared__ f16 Bsh2[128 * 32];
  int b = blockIdx.x;
  int g = (b & 7) * per + (b >> 3);
  if (g >= mt * nt) return;   // block-uniform exit (barrier-safe)
  int tm = (g / nt) * 128, tn = (g % nt) * 128;
  int tid = threadIdx.x, l = tid & 63, w = tid >> 6;

  const f16* ag[2]; const f16* bg[2];
  uint32_t lof[2];
  #pragma unroll
  for (int j = 0; j < 2; ++j) {
    int rl = w * 32 + j * 16 + (l >> 2);
    int ck = l & 3;
    int lc = ck ^ ((rl >> 1) & 3);       // XOR chunk swizzle (R3-proven)
    int gr = tm + rl; if (gr > M - 1) gr = M - 1;
    int gn = tn + rl; if (gn > N - 1) gn = N - 1;
    ag[j] = A + (size_t)gr * lda + lc * 8;
    bg[j] = Bt + (size_t)gn * K + lc * 8;
    lof[j] = (uint32_t)(w * 32 + j * 16) * 64;
  }

  int wm = (w >> 1) * 64, wn = (w & 1) * 64;
  int q = l >> 4, l15 = l & 15;
  uint32_t aoffb[4], boffb[4];
  #pragma unroll
  for (int i2 = 0; i2 < 4; ++i2) {
    int m = wm + i2 * 16 + l15;
    int n2 = wn + i2 * 16 + l15;
    aoffb[i2] = (uint32_t)(m * 32 + (q ^ ((m >> 1) & 3)) * 8) * 2;
    boffb[i2] = (uint32_t)(n2 * 32 + (q ^ ((n2 >> 1) & 3)) * 8) * 2;
  }

  floatx4 acc[4][4];
  #pragma unroll
  for (int i2 = 0; i2 < 4; ++i2)
    #pragma unroll
    for (int j2 = 0; j2 < 4; ++j2) acc[i2][j2] = (floatx4){0.f, 0.f, 0.f, 0.f};

  int nk = K >> 5;   // callers guarantee nk >= 2
  STAGE(Ash0, Bsh0);
  STAGE(Ash1, Bsh1);

  int i = 0;
  while (true) {
    PHASE(Ash0, Bsh0, Ash2, Bsh2); if (i == nk) break;
    PHASE(Ash1, Bsh1, Ash0, Bsh0); if (i == nk) break;
    PHASE(Ash2, Bsh2, Ash1, Bsh1); if (i == nk) break;
  }

  // epilogue: C/D layout col=lane&15, row=quad*4+reg (m89-verified)
  #pragma unroll
  for (int ni = 0; ni < 4; ++ni) {
    int col = tn + wn + ni * 16 + l15;
    if (col >= N) continue;
    float bv = bias ? bias[col] : 0.f;
    #pragma unroll
    for (int mi = 0; mi < 4; ++mi) {
      int rowb = tm + wm + mi * 16 + q * 4;
      #pragma unroll
      for (int r = 0; r < 4; ++r) {
        int row = rowb + r;
        if (row < M) {
          float v = acc[mi][ni][r] + bv;
          if (relu) v = fmaxf(v, 0.f);
          if (outf) ((float*)Cv)[(size_t)row * ldc + col] = v;
          else      ((f16*)Cv)[(size_t)row * ldc + col] = (f16)v;
        }
      }
    }
  }
}

// ---------------------------------------------------------------------------
// small GEMM (N<256 shapes): R3's 128x128 dbuf kernel, unchanged (proven)
// ---------------------------------------------------------------------------
__global__ __launch_bounds__(256)
void k_gemm_small(const f16* __restrict__ A, int lda,
                  const f16* __restrict__ Bt,
                  void* __restrict__ Cv, int ldc,
                  const float* __restrict__ bias, int relu, int outf,
                  int M, int N, int K, int mt, int nt, int per) {
  __shared__ f16 Ash[2][128 * 32];
  __shared__ f16 Bsh[2][128 * 32];
  int b = blockIdx.x;
  int g = (b & 7) * per + (b >> 3);
  if (g >= mt * nt) return;
  int tm = (g / nt) * 128, tn = (g % nt) * 128;
  int tid = threadIdx.x, l = tid & 63, w = tid >> 6;

  const f16* ag[2]; const f16* bg[2];
  uint32_t lof[2];
  #pragma unroll
  for (int j = 0; j < 2; ++j) {
    int rl = w * 32 + j * 16 + (l >> 2);
    int ck = l & 3;
    int lc = ck ^ ((rl >> 1) & 3);
    int gr = tm + rl; if (gr > M - 1) gr = M - 1;
    int gn = tn + rl; if (gn > N - 1) gn = N - 1;
    ag[j] = A + (size_t)gr * lda + lc * 8;
    bg[j] = Bt + (size_t)gn * K + lc * 8;
    lof[j] = (uint32_t)(w * 32 + j * 16) * 64;
  }

  int wm = (w >> 1) * 64, wn = (w & 1) * 64;
  int q = l >> 4, l15 = l & 15;
  uint32_t aoffb[4], boffb[4];
  #pragma unroll
  for (int i = 0; i < 4; ++i) {
    int m = wm + i * 16 + l15;
    int n2 = wn + i * 16 + l15;
    aoffb[i] = (uint32_t)(m * 32 + (q ^ ((m >> 1) & 3)) * 8) * 2;
    boffb[i] = (uint32_t)(n2 * 32 + (q ^ ((n2 >> 1) & 3)) * 8) * 2;
  }

  floatx4 acc[4][4];
  #pragma unroll
  for (int i = 0; i < 4; ++i)
    #pragma unroll
    for (int j = 0; j < 4; ++j) acc[i][j] = (floatx4){0.f, 0.f, 0.f, 0.f};

  int nk = K >> 5;
  #pragma unroll
  for (int j = 0; j < 2; ++j) {
    GLL(ag[j], (char*)Ash + lof[j]);
    GLL(bg[j], (char*)Bsh + lof[j]);
    ag[j] += 32; bg[j] += 32;
  }

  for (int i = 0; i < nk; ++i) {
    __syncthreads();
    if (i + 1 < nk) {
      uint32_t d = ((i + 1) & 1) ? 8192u : 0u;
      #pragma unroll
      for (int j = 0; j < 2; ++j) {
        GLL(ag[j], (char*)Ash + d + lof[j]);
        GLL(bg[j], (char*)Bsh + d + lof[j]);
        ag[j] += 32; bg[j] += 32;
      }
    }
    uint32_t s = (i & 1) ? 8192u : 0u;
    f16x8 af[4], bf[4];
    #pragma unroll
    for (int ii = 0; ii < 4; ++ii) {
      af[ii] = *(const f16x8*)((const char*)Ash + s + aoffb[ii]);
      bf[ii] = *(const f16x8*)((const char*)Bsh + s + boffb[ii]);
    }
    #pragma unroll
    for (int mi = 0; mi < 4; ++mi)
      #pragma unroll
      for (int ni = 0; ni < 4; ++ni)
        acc[mi][ni] = __builtin_amdgcn_mfma_f32_16x16x32_f16(af[mi], bf[ni], acc[mi][ni], 0, 0, 0);
  }

  #pragma unroll
  for (int ni = 0; ni < 4; ++ni) {
    int col = tn + wn + ni * 16 + l15;
    if (col >= N) continue;
    float bv = bias ? bias[col] : 0.f;
    #pragma unroll
    for (int mi = 0; mi < 4; ++mi) {
      int rowb = tm + wm + mi * 16 + q * 4;
      #pragma unroll
      for (int r = 0; r < 4; ++r) {
        int row = rowb + r;
        if (row < M) {
          float v = acc[mi][ni][r] + bv;
          if (relu) v = fmaxf(v, 0.f);
          if (outf) ((float*)Cv)[(size_t)row * ldc + col] = v;
          else      ((f16*)Cv)[(size_t)row * ldc + col] = (f16)v;
        }
      }
    }
  }
}

// ---------------------------------------------------------------------------
// host orchestration
// ---------------------------------------------------------------------------
extern "C" void kernel_launch(void* const* d_in, const int* in_sizes, int n_in,
                              void* d_out, int out_size, void* d_ws, size_t ws_size,
                              hipStream_t stream) {
  (void)in_sizes; (void)n_in; (void)out_size; (void)ws_size;
  const int NL = 50000, NJ = 25000, EL = 400000, EJ = 100000;

  const float* x_l  = (const float*)d_in[0];
  const float* x_j  = (const float*)d_in[1];
  const int*   ei_l = (const int*)d_in[2];
  const int*   ei_j = (const int*)d_in[3];
  const float* lgW1 = (const float*)d_in[4];  const float* lgb1 = (const float*)d_in[5];
  const float* lgg1 = (const float*)d_in[6];  const float* lgbe1= (const float*)d_in[7];
  const float* lgW2 = (const float*)d_in[8];  const float* lgb2 = (const float*)d_in[9];
  const float* lgg2 = (const float*)d_in[10]; const float* lgbe2= (const float*)d_in[11];
  const float* lgfcW= (const float*)d_in[12]; const float* lgfcb= (const float*)d_in[13];
  const float* flW1 = (const float*)d_in[14]; const float* flb1 = (const float*)d_in[15];
  const float* flW2 = (const float*)d_in[16]; const float* flb2 = (const float*)d_in[17];
  const float* flW3 = (const float*)d_in[18]; const float* flb3 = (const float*)d_in[19];
  const float* jgW1 = (const float*)d_in[20]; const float* jgb1 = (const float*)d_in[21];
  const float* jgg1 = (const float*)d_in[22]; const float* jgbe1= (const float*)d_in[23];
  const float* jgW2 = (const float*)d_in[24]; const float* jgb2 = (const float*)d_in[25];
  const float* jgg2 = (const float*)d_in[26]; const float* jgbe2= (const float*)d_in[27];
  const float* jgfcW= (const float*)d_in[28]; const float* jgfcb= (const float*)d_in[29];
  const float* fjW1 = (const float*)d_in[30]; const float* fjb1 = (const float*)d_in[31];
  const float* fjW2 = (const float*)d_in[32]; const float* fjb2 = (const float*)d_in[33];

  char* ws = (char*)d_ws;
  size_t off = 0;
  auto alloc = [&](size_t bytes) -> char* {
    char* p = ws + off;
    off += (bytes + 255) & ~(size_t)255;
    return p;
  };

  f16* cat16 = (f16*)alloc((size_t)NL * 1792 * 2);
  f16* hA    = (f16*)alloc((size_t)NL * 1024 * 2);
  f16* hB    = (f16*)alloc((size_t)NL * 1024 * 2);
  f16* xw16  = (f16*)hB;
  f16* catJ  = (f16*)alloc((size_t)NJ * 448 * 2);
  f16* hJA   = (f16*)alloc((size_t)NJ * 256 * 2);
  f16* hJB   = (f16*)alloc((size_t)NJ * 64 * 2);
  f16* xwJ   = (f16*)hB;

  f16* W1t   = (f16*)alloc((size_t)1024 * 512 * 2);
  f16* W2t   = (f16*)alloc((size_t)512 * 256 * 2);
  f16* fcWt  = (f16*)alloc((size_t)1792 * 1024 * 2);
  f16* flW1t = (f16*)alloc((size_t)1024 * 1024 * 2);
  f16* flW2t = (f16*)alloc((size_t)1024 * 1024 * 2);
  f16* flW3t = (f16*)alloc((size_t)1024 * 16 * 2);
  f16* jW1t  = (f16*)alloc((size_t)256 * 128 * 2);
  f16* jW2t  = (f16*)alloc((size_t)128 * 64 * 2);
  f16* jfcWt = (f16*)alloc((size_t)448 * 256 * 2);
  f16* fjW1t = (f16*)alloc((size_t)256 * 64 * 2);
  f16* fjW2t = (f16*)alloc((size_t)64 * 4 * 2);

  int* zero0 = (int*)alloc(((size_t)2 * NL + 2 * NJ + 1920) * 4);
  int* cntL  = zero0;
  int* fillL = cntL + NL;
  int* cntJ  = fillL + NL;
  int* fillJ = cntJ + NJ;
  float* stats = (float*)(fillJ + NJ);
  float* sum1L = stats;        float* sq1L = stats + 512;
  float* sum2L = stats + 1024; float* sq2L = stats + 1280;
  float* sum1J = stats + 1536; float* sq1J = stats + 1664;
  float* sum2J = stats + 1792; float* sq2J = stats + 1856;

  int* rsL   = (int*)alloc((size_t)(NL + 4) * 4);
  int* cixL  = (int*)alloc((size_t)EL * 4);
  float* disL= (float*)alloc((size_t)NL * 4);
  int* rsJ   = (int*)alloc((size_t)(NJ + 4) * 4);
  int* cixJ  = (int*)alloc((size_t)EJ * 4);
  float* disJ= (float*)alloc((size_t)NJ * 4);

  auto cdiv = [](int a, int b) { return (a + b - 1) / b; };

  auto gemm = [&](const f16* A, int lda, const f16* Bt, void* Cc, int ldc,
                  const float* bias, int relu, int outf, int M, int N, int K) {
    int mt = cdiv(M, 128), nt = cdiv(N, 128);
    int per = cdiv(mt * nt, 8);
    if (N >= 256)
      k_gemm_big<<<8 * per, 256, 0, stream>>>(A, lda, Bt, Cc, ldc, bias, relu, outf,
                                              M, N, K, mt, nt, per);
    else
      k_gemm_small<<<8 * per, 256, 0, stream>>>(A, lda, Bt, Cc, ldc, bias, relu, outf,
                                                M, N, K, mt, nt, per);
  };
  auto bn = [&](f16* v, int ldd, int coff, int n, int C,
                float* sum, float* sumsq, const float* gamma, const float* beta) {
    dim3 gs(cdiv(C, 256), cdiv(n, 128));
    k_stats<<<gs, 256, 0, stream>>>(v, ldd, coff, n, C, sum, sumsq);
    k_bnapply_ip<<<cdiv(n * (C >> 2), 256), 256, 0, stream>>>(
        v, ldd, coff, n, C, sum, sumsq, gamma, beta, 1.0f / (float)n);
  };

  hipMemsetAsync(zero0, 0, ((size_t)2 * NL + 2 * NJ + 1920) * 4, stream);

  {
    WtBatch B2; int base = 0, nj = 0;
    auto add = [&](const float* W, f16* Wt, int K, int N) {
      int tK = cdiv(K, 32), tN = cdiv(N, 32);
      B2.j[nj++] = WtJob{W, Wt, K, N, tN, base};
      base += tK * tN;
    };
    add(lgW1, W1t, 1024, 512);
    add(lgW2, W2t, 512, 256);
    add(lgfcW, fcWt, 1792, 1024);
    add(flW1, flW1t, 1024, 1024);
    add(flW2, flW2t, 1024, 1024);
    add(flW3, flW3t, 1024, 10);
    add(jgW1, jW1t, 256, 128);
    add(jgW2, jW2t, 128, 64);
    add(jgfcW, jfcWt, 448, 256);
    add(fjW1, fjW1t, 256, 64);
    add(fjW2, fjW2t, 64, 3);
    B2.njobs = nj; B2.ntiles = base;
    k_wt_tiled<<<base, 256, 0, stream>>>(B2);
  }

  k_cvt_cols<<<cdiv(NL * 256, 256), 256, 0, stream>>>(x_l, cat16, NL, 1024, 1792, 0);
  k_cvt_cols<<<cdiv(NJ * 64, 256), 256, 0, stream>>>(x_j, catJ, NJ, 256, 448, 0);

  k_count2<<<cdiv(EL + EJ, 256), 256, 0, stream>>>(ei_l + EL, EL, cntL, ei_j + EJ, EJ, cntJ);
  k_scan4_dual<<<2, 1024, 0, stream>>>(cntL, NL, rsL, disL, cntJ, NJ, rsJ, disJ);
  k_fill2<<<cdiv(EL + EJ, 256), 256, 0, stream>>>(ei_l, EL, rsL, fillL, cixL,
                                                  ei_j, EJ, rsJ, fillJ, cixJ);

  // ================= line branch =================
  gemm(cat16, 1792, W1t, xw16, 512, nullptr, 0, 0, NL, 512, 1024);
  k_gather_f16<8><<<cdiv(NL, 4), 256, 0, stream>>>(xw16, 512, rsL, cixL, disL, lgb1,
                                                   cat16, 1792, 1024, NL);
  bn(cat16, 1792, 1024, NL, 512, sum1L, sq1L, lgg1, lgbe1);

  gemm(cat16 + 1024, 1792, W2t, xw16, 256, nullptr, 0, 0, NL, 256, 512);
  k_gather_f16<4><<<cdiv(NL, 4), 256, 0, stream>>>(xw16, 256, rsL, cixL, disL, lgb2,
                                                   cat16, 1792, 1536, NL);
  bn(cat16, 1792, 1536, NL, 256, sum2L, sq2L, lgg2, lgbe2);

  gemm(cat16, 1792, fcWt, hA, 1024, lgfcb, 1, 0, NL, 1024, 1792);
  gemm(hA, 1024, flW1t, hB, 1024, flb1, 1, 0, NL, 1024, 1024);
  gemm(hB, 1024, flW2t, hA, 1024, flb2, 1, 0, NL, 1024, 1024);
  gemm(hA, 1024, flW3t, (float*)d_out, 10, flb3, 0, 1, NL, 10, 1024);

  // ================= junction branch =================
  gemm(catJ, 448, jW1t, xwJ, 128, nullptr, 0, 0, NJ, 128, 256);
  k_gather_f16<2><<<cdiv(NJ, 4), 256, 0, stream>>>(xwJ, 128, rsJ, cixJ, disJ, jgb1,
                                                   catJ, 448, 256, NJ);
  bn(catJ, 448, 256, NJ, 128, sum1J, sq1J, jgg1, jgbe1);

  gemm(catJ + 256, 448, jW2t, xwJ, 64, nullptr, 0, 0, NJ, 64, 128);
  k_gather_f16<1><<<cdiv(NJ, 4), 256, 0, stream>>>(xwJ, 64, rsJ, cixJ, disJ, jgb2,
                                                   catJ, 448, 384, NJ);
  bn(catJ, 448, 384, NJ, 64, sum2J, sq2J, jgg2, jgbe2);

  gemm(catJ, 448, jfcWt, hJA, 256, jgfcb, 1, 0, NJ, 256, 448);
  gemm(hJA, 256, fjW1t, hJB, 64, fjb1, 1, 0, NJ, 64, 256);
  gemm(hJB, 64, fjW2t, (float*)d_out + (size_t)NL * 10, 3, fjb2, 0, 1, NJ, 3, 64);
}